// Round 3
// baseline (1037.499 us; speedup 1.0000x reference)
//
#include <hip/hip_runtime.h>

typedef unsigned short u16;
typedef unsigned int u32;
typedef __attribute__((ext_vector_type(8))) short short8;
typedef __attribute__((ext_vector_type(4))) float floatx4;

#define E_ 1024
#define B_ 256
#define M_ 196
#define H_ 8
#define DH_ 128
#define MID_ 64

__device__ __forceinline__ u16 f2bf(float f){
  union { float f; u32 u; } v; v.f = f;
  return (u16)((v.u + (((v.u >> 16) & 1u) + 0x7fffu)) >> 16);
}
__device__ __forceinline__ float bf2f(u16 h){
  union { u32 u; float f; } v; v.u = ((u32)h) << 16;
  return v.f;
}
// pack two floats to bf16x2
__device__ __forceinline__ u32 pack_bf2(float a, float b){
  u32 ua = __float_as_uint(a) + 0x8000u;
  u32 ub = __float_as_uint(b) + 0x8000u;
  return __builtin_amdgcn_perm(ub, ua, 0x07060302);
}
// async global->LDS, 16B per lane; LDS dest = base + lane*16 (wave-uniform base)
__device__ __forceinline__ void gl_lds16(const void* g, void* l){
  __builtin_amdgcn_global_load_lds(
      (const __attribute__((address_space(1))) u32*)g,
      (__attribute__((address_space(3))) u32*)l, 16, 0, 0);
}

// ---------------------------------------------------------------------------
// Kernel 0: convert+transpose the 4 projection weight matrices to bf16 [col][k].
// ---------------------------------------------------------------------------
__global__ __launch_bounds__(256) void wconv_kernel(
    const float* __restrict__ Wq, const float* __restrict__ Wk,
    const float* __restrict__ Wv1, const float* __restrict__ Wv2,
    u16* __restrict__ Wt)
{
  __shared__ u16 tile[64][72];
  const float* W = (blockIdx.z == 0) ? Wq : (blockIdx.z == 1) ? Wk
                 : (blockIdx.z == 2) ? Wv1 : Wv2;
  u16* out = Wt + (size_t)blockIdx.z * (E_ * E_);
  int k0 = blockIdx.x * 64, c0 = blockIdx.y * 64;
  int tx = threadIdx.x & 63, ty = threadIdx.x >> 6;
  #pragma unroll
  for (int i = 0; i < 16; i++){
    int k = ty * 16 + i;
    tile[k][tx] = f2bf(W[(size_t)(k0 + k) * E_ + c0 + tx]);
  }
  __syncthreads();
  #pragma unroll
  for (int i = 0; i < 16; i++){
    int c = ty * 16 + i;
    out[(size_t)(c0 + c) * E_ + k0 + tx] = tile[tx][c];
  }
}

// ---------------------------------------------------------------------------
// Kernel 1: fused GEMM + bias + celu + group-norm.
// 128x128 tile, BK=64, 4 waves as 2x2 (each 64 rows x 64 cols), acc[4][4]
// = 64 AGPRs -> 3 blocks/CU (was 128 AGPRs -> 2 blocks/CU).
// A path: fp32 global -> regs (prefetched for kt+1 during compute of kt)
//   -> packed bf16 once per element -> LDS [row][64] with XOR chunk swizzle
//   slot = chunk ^ (row&7)  (2-way on write and read = free).
// B path: global_load_lds 16B with PRE-SWIZZLED global source (m173): lane l
//   of staging call loads global chunk (l&7)^(l>>3) so linear LDS dest ends
//   up XOR-swizzled; frag read uses slot = chunk ^ (col&7) -> conflict-free
//   despite 128B row stride.
// Epilogue: per-row s,s2 reduced in-wave over its 64-col half, combined
// across ch-waves through a 2KB LDS buffer (group = 128 cols).
// ---------------------------------------------------------------------------
__global__ __launch_bounds__(256, 3) void proj_kernel(
    const float* __restrict__ query, const float* __restrict__ key,
    const float* __restrict__ value1, const float* __restrict__ value2,
    const float* __restrict__ bq, const float* __restrict__ gqw, const float* __restrict__ gqb,
    const float* __restrict__ bk, const float* __restrict__ gkw, const float* __restrict__ gkb,
    const float* __restrict__ bv1, const float* __restrict__ gv1w, const float* __restrict__ gv1b,
    const float* __restrict__ bv2, const float* __restrict__ gv2w, const float* __restrict__ gv2b,
    const u16* __restrict__ Wt,
    u16* __restrict__ qout, u16* __restrict__ kout,
    u16* __restrict__ v1out, u16* __restrict__ v2out)
{
  __shared__ u16 a_lds[128 * 64];     // 16 KB bf16, row stride 128B, XOR-swizzled
  __shared__ u16 b_lds[128 * 64];     // 16 KB bf16, col stride 128B, XOR-swizzled
  __shared__ float ps[128][2][2];     // per-row {s,s2} partials per ch-half

  const int tid = threadIdx.x;
  const int w = tid >> 6, lane = tid & 63, qd = lane >> 4, lr = lane & 15;
  const int rh = w >> 1, ch = w & 1;

  const int mtb = blockIdx.y;
  const float* X; const float *bias, *gw, *gb; u16* out; int row0, matsel;
  if (mtb < 392)      { X = key;    bias = bk;  gw = gkw;  gb = gkb;  out = kout;  row0 = mtb * 128;         matsel = 1; }
  else if (mtb < 784) { X = value2; bias = bv2; gw = gv2w; gb = gv2b; out = v2out; row0 = (mtb - 392) * 128; matsel = 3; }
  else if (mtb < 786) { X = query;  bias = bq;  gw = gqw;  gb = gqb;  out = qout;  row0 = (mtb - 784) * 128; matsel = 0; }
  else                { X = value1; bias = bv1; gw = gv1w; gb = gv1b; out = v1out; row0 = (mtb - 786) * 128; matsel = 2; }
  const int col0 = blockIdx.x * 128;

  // A staging: thread t handles row t>>1, 32-float half t&1 of the BK=64 slab.
  const int ar = tid >> 1, ah = tid & 1, rsw = ar & 7;
  const float* aSrc = X + (size_t)(row0 + ar) * E_ + ah * 32;
  // B staging: wave w covers cols [w*32,+32) in 4 calls of 8 cols; lane l ->
  // col +(l>>3), loads pre-swizzled global chunk (l&7)^(l>>3).
  const u16* bSrc = Wt + (size_t)matsel * (E_ * E_)
                  + (size_t)(col0 + w * 32 + (lane >> 3)) * E_
                  + ((lane & 7) ^ (lane >> 3)) * 8;

  floatx4 acc[4][4];
  #pragma unroll
  for (int i = 0; i < 4; i++)
    #pragma unroll
    for (int j = 0; j < 4; j++){
      floatx4 z = {0.f, 0.f, 0.f, 0.f};
      acc[i][j] = z;
    }

  // prologue: A regs for kt=0
  float4 aRegs[8];
  #pragma unroll
  for (int j = 0; j < 8; j++) aRegs[j] = *(const float4*)(aSrc + j * 4);

  for (int kt = 0; kt < 16; kt++){
    const int k0 = kt * 64;
    __syncthreads();                    // prev compute done with LDS
    // B: async global->LDS (linear dest, swizzled source)
    #pragma unroll
    for (int c = 0; c < 4; c++)
      gl_lds16(bSrc + (size_t)c * 8 * E_ + k0, &b_lds[(w * 32 + c * 8) * 64]);
    // A: convert prefetched regs -> swizzled bf16 LDS
    #pragma unroll
    for (int j2 = 0; j2 < 4; j2++){
      union { u32 u[4]; int4 v; } pk;
      pk.u[0] = pack_bf2(aRegs[j2 * 2].x,     aRegs[j2 * 2].y);
      pk.u[1] = pack_bf2(aRegs[j2 * 2].z,     aRegs[j2 * 2].w);
      pk.u[2] = pack_bf2(aRegs[j2 * 2 + 1].x, aRegs[j2 * 2 + 1].y);
      pk.u[3] = pack_bf2(aRegs[j2 * 2 + 1].z, aRegs[j2 * 2 + 1].w);
      *(int4*)&a_lds[ar * 64 + (((ah * 4 + j2) ^ rsw)) * 8] = pk.v;
    }
    __syncthreads();                    // staging visible (vmcnt+lgkm drain)
    // prefetch A for kt+1: latency hides under the MFMA phase below
    if (kt < 15){
      #pragma unroll
      for (int j = 0; j < 8; j++)
        aRegs[j] = *(const float4*)(aSrc + k0 + 64 + j * 4);
    }
    // compute: 2 sub-steps of K=32
    #pragma unroll
    for (int kk = 0; kk < 2; kk++){
      const int cs = kk * 4 + qd;       // this lane's 16B chunk index in [0,8)
      short8 bfr[4];
      #pragma unroll
      for (int nt = 0; nt < 4; nt++)
        bfr[nt] = *(const short8*)&b_lds[(ch * 64 + nt * 16 + lr) * 64 + (cs ^ (lr & 7)) * 8];
      #pragma unroll
      for (int m2 = 0; m2 < 4; m2++){
        short8 afr = *(const short8*)&a_lds[(rh * 64 + m2 * 16 + lr) * 64 + (cs ^ (lr & 7)) * 8];
        #pragma unroll
        for (int nt = 0; nt < 4; nt++)
          acc[m2][nt] = __builtin_amdgcn_mfma_f32_16x16x32_bf16(afr, bfr[nt], acc[m2][nt], 0, 0, 0);
      }
    }
  }

  // Epilogue: bias + celu; per-row stats over the full 128-col group
  // (in-wave over this wave's 64 cols, then cross-ch combine in LDS).
  float biasv[4], gwv[4], gbv[4];
  #pragma unroll
  for (int nt = 0; nt < 4; nt++){
    int c = col0 + ch * 64 + nt * 16 + lr;
    biasv[nt] = bias[c]; gwv[nt] = gw[c]; gbv[nt] = gb[c];
  }
  #pragma unroll
  for (int m2 = 0; m2 < 4; m2++){
    #pragma unroll
    for (int r = 0; r < 4; r++){
      float s = 0.f, s2 = 0.f;
      #pragma unroll
      for (int nt = 0; nt < 4; nt++){
        float x = acc[m2][nt][r] + biasv[nt];
        x = (x > 0.f) ? x : 1.3f * expm1f(x * (1.0f / 1.3f));
        acc[m2][nt][r] = x;
        s += x; s2 += x * x;
      }
      #pragma unroll
      for (int off = 1; off < 16; off <<= 1){
        s  += __shfl_xor(s,  off, 64);
        s2 += __shfl_xor(s2, off, 64);
      }
      if (lr == 0){
        int row = rh * 64 + m2 * 16 + qd * 4 + r;
        ps[row][ch][0] = s; ps[row][ch][1] = s2;
      }
    }
  }
  __syncthreads();
  #pragma unroll
  for (int m2 = 0; m2 < 4; m2++){
    #pragma unroll
    for (int r = 0; r < 4; r++){
      int row = rh * 64 + m2 * 16 + qd * 4 + r;
      float s  = ps[row][0][0] + ps[row][1][0];
      float s2 = ps[row][0][1] + ps[row][1][1];
      float mean = s * 0.0078125f;
      float var  = s2 * 0.0078125f - mean * mean;
      float rstd = rsqrtf(var + 1e-5f);
      size_t base = (size_t)(row0 + row) * E_ + col0 + ch * 64;
      #pragma unroll
      for (int nt = 0; nt < 4; nt++)
        out[base + nt * 16 + lr] = f2bf((acc[m2][nt][r] - mean) * rstd * gwv[nt] + gbv[nt]);
    }
  }
}

// ---------------------------------------------------------------------------
// Kernel 2: per-(b,h) attention. (unchanged this round)
// ---------------------------------------------------------------------------
__global__ __launch_bounds__(256) void attn_kernel(
    const u16* __restrict__ qproj, const u16* __restrict__ kproj,
    const u16* __restrict__ v1proj, const u16* __restrict__ v2proj,
    const int* __restrict__ mask,
    const float* __restrict__ Wb, const float* __restrict__ bb,
    const float* __restrict__ Ws, const float* __restrict__ bs,
    const float* __restrict__ Wc, const float* __restrict__ bc,
    float* __restrict__ outp)
{
  __shared__ u16 wbt[64 * 136];      // B' = diag(q)*Wb, [n][k], stride 136
  __shared__ float qv[128];
  __shared__ float mrow[208];
  __shared__ float logitv[208];
  __shared__ float hsum_l[4][64];
  __shared__ float wexpv[208];
  __shared__ float poolv[64];
  __shared__ float v2acc[4][128];
  __shared__ float red[8];

  const int tid = threadIdx.x;
  const int w = tid >> 6, lane = tid & 63, qd = lane >> 4, lr = lane & 15;
  const int b = blockIdx.y, h = blockIdx.x;

  const u16* kbase  = kproj  + (size_t)b * M_ * E_ + h * DH_;
  const u16* v2base = v2proj + (size_t)b * M_ * E_ + h * DH_;

  if (tid < 128) qv[tid] = bf2f(qproj[(size_t)b * E_ + h * DH_ + tid]);
  if (tid < 208) mrow[tid] = (tid < M_) ? (float)mask[b * M_ + tid] : 0.f;
  __syncthreads();

  {
    int n = tid & 63, kb = (tid >> 6) * 32;
    #pragma unroll
    for (int kk = 0; kk < 32; kk++)
      wbt[n * 136 + kb + kk] = f2bf(qv[kb + kk] * Wb[(kb + kk) * MID_ + n]);
  }
  __syncthreads();

  float wsv[4], bbv[4];
  #pragma unroll
  for (int nt = 0; nt < 4; nt++){ wsv[nt] = Ws[nt * 16 + lr]; bbv[nt] = bb[nt * 16 + lr]; }
  const float bsv = bs[0];
  float hs[4] = {0, 0, 0, 0};

  for (int mt = w; mt < 13; mt += 4){
    int mrow_g = mt * 16 + lr;
    int mcl = (mrow_g < M_) ? mrow_g : (M_ - 1);   // clamp padded rows
    const u16* arow = kbase + (size_t)mcl * E_;
    floatx4 hacc[4];
    #pragma unroll
    for (int nt = 0; nt < 4; nt++){ floatx4 z = {0.f, 0.f, 0.f, 0.f}; hacc[nt] = z; }
    #pragma unroll
    for (int kc = 0; kc < 4; kc++){
      short8 afr = *(const short8*)(arow + kc * 32 + qd * 8);
      #pragma unroll
      for (int nt = 0; nt < 4; nt++){
        short8 bfr = *(const short8*)&wbt[(nt * 16 + lr) * 136 + kc * 32 + qd * 8];
        hacc[nt] = __builtin_amdgcn_mfma_f32_16x16x32_bf16(afr, bfr, hacc[nt], 0, 0, 0);
      }
    }
    float lp[4] = {0, 0, 0, 0};
    #pragma unroll
    for (int nt = 0; nt < 4; nt++){
      #pragma unroll
      for (int r = 0; r < 4; r++){
        float hv = hacc[nt][r] + bbv[nt];
        hv = fmaxf(hv, 0.f);
        lp[r] += hv * wsv[nt];
        hs[nt] += mrow[mt * 16 + qd * 4 + r] * hv;
      }
    }
    #pragma unroll
    for (int r = 0; r < 4; r++){
      float a = lp[r];
      #pragma unroll
      for (int off = 1; off < 16; off <<= 1) a += __shfl_xor(a, off, 64);
      if (lr == 0) logitv[mt * 16 + qd * 4 + r] = a + bsv;
    }
  }
  #pragma unroll
  for (int nt = 0; nt < 4; nt++){
    hs[nt] += __shfl_xor(hs[nt], 16, 64);
    hs[nt] += __shfl_xor(hs[nt], 32, 64);
  }
  if (lane < 16){
    #pragma unroll
    for (int nt = 0; nt < 4; nt++) hsum_l[w][nt * 16 + lane] = hs[nt];
  }
  __syncthreads();

  if (w == 0){
    float s = 0.f;
    for (int m = lane; m < M_; m += 64) s += mrow[m];
    #pragma unroll
    for (int off = 1; off < 64; off <<= 1) s += __shfl_xor(s, off, 64);
    if (lane == 0) red[0] = s;
  } else if (w == 1){
    float mx = -1e30f;
    for (int m = lane; m < M_; m += 64) if (mrow[m] > 0.5f) mx = fmaxf(mx, logitv[m]);
    #pragma unroll
    for (int off = 1; off < 64; off <<= 1) mx = fmaxf(mx, __shfl_xor(mx, off, 64));
    if (lane == 0) red[1] = mx;
  } else if (w == 2){
    poolv[lane & 63] = hsum_l[0][lane & 63] + hsum_l[1][lane & 63]
                     + hsum_l[2][lane & 63] + hsum_l[3][lane & 63];
  }
  __syncthreads();
  const float cnt = red[0], mx = red[1];
  if (tid < 208)
    wexpv[tid] = (tid < M_ && mrow[tid] > 0.5f) ? expf(logitv[tid] - mx) : 0.f;
  __syncthreads();
  if (w == 0){
    float s = 0.f;
    for (int m = lane; m < M_; m += 64) s += wexpv[m];
    #pragma unroll
    for (int off = 1; off < 64; off <<= 1) s += __shfl_xor(s, off, 64);
    if (lane == 0) red[2] = s;
  } else if (w == 1){
    poolv[lane & 63] = poolv[lane & 63] / cnt;
  }
  __syncthreads();
  const float S = red[2];

  // v2 pooling: per iteration a wave covers rows {it*16 + w*4 + qd}, 16B/lane.
  {
    float ac[8] = {0, 0, 0, 0, 0, 0, 0, 0};
    #pragma unroll
    for (int it = 0; it < 13; it++){
      int m = it * 16 + w * 4 + qd;
      if (m < M_){
        float we = wexpv[m];
        uint4 u = *(const uint4*)(v2base + (size_t)m * E_ + lr * 8);
        ac[0] += we * bf2f((u16)(u.x & 0xffff));
        ac[1] += we * bf2f((u16)(u.x >> 16));
        ac[2] += we * bf2f((u16)(u.y & 0xffff));
        ac[3] += we * bf2f((u16)(u.y >> 16));
        ac[4] += we * bf2f((u16)(u.z & 0xffff));
        ac[5] += we * bf2f((u16)(u.z >> 16));
        ac[6] += we * bf2f((u16)(u.w & 0xffff));
        ac[7] += we * bf2f((u16)(u.w >> 16));
      }
    }
    #pragma unroll
    for (int j = 0; j < 8; j++){
      ac[j] += __shfl_xor(ac[j], 16, 64);
      ac[j] += __shfl_xor(ac[j], 32, 64);
    }
    if (qd == 0){
      #pragma unroll
      for (int j = 0; j < 8; j++) v2acc[w][lr * 8 + j] = ac[j];
    }
  }
  __syncthreads();

  if (tid < 128){
    float a = 0.f;
    #pragma unroll 8
    for (int j = 0; j < 64; j++) a += poolv[j] * Wc[j * DH_ + tid];
    float acv = 1.f / (1.f + expf(-(a + bc[tid])));
    float vp = (v2acc[0][tid] + v2acc[1][tid] + v2acc[2][tid] + v2acc[3][tid]) / S;
    float o = bf2f(v1proj[(size_t)b * E_ + h * DH_ + tid]) * vp * acv;
    outp[(size_t)b * E_ + h * DH_ + tid] = o;
  }
}

// ---------------------------------------------------------------------------
extern "C" void kernel_launch(void* const* d_in, const int* in_sizes, int n_in,
                              void* d_out, int out_size, void* d_ws, size_t ws_size,
                              hipStream_t stream)
{
  const float* query  = (const float*)d_in[0];
  const float* key    = (const float*)d_in[1];
  const int*   mask   = (const int*)d_in[2];
  const float* value1 = (const float*)d_in[3];
  const float* value2 = (const float*)d_in[4];
  const float* Wq  = (const float*)d_in[5];
  const float* bq  = (const float*)d_in[6];
  const float* gqw = (const float*)d_in[7];
  const float* gqb = (const float*)d_in[8];
  const float* Wk  = (const float*)d_in[9];
  const float* bk  = (const float*)d_in[10];
  const float* gkw = (const float*)d_in[11];
  const float* gkb = (const float*)d_in[12];
  const float* Wv1 = (const float*)d_in[13];
  const float* bv1 = (const float*)d_in[14];
  const float* gv1w= (const float*)d_in[15];
  const float* gv1b= (const float*)d_in[16];
  const float* Wv2 = (const float*)d_in[17];
  const float* bv2 = (const float*)d_in[18];
  const float* gv2w= (const float*)d_in[19];
  const float* gv2b= (const float*)d_in[20];
  const float* Wb  = (const float*)d_in[21];
  const float* bb  = (const float*)d_in[22];
  const float* Ws  = (const float*)d_in[23];
  const float* bs  = (const float*)d_in[24];
  const float* Wc  = (const float*)d_in[25];
  const float* bc  = (const float*)d_in[26];

  const size_t NK = (size_t)B_ * M_;           // 50176 rows
  u16* kout  = (u16*)d_ws;
  u16* v2out = kout  + NK * E_;
  u16* qout  = v2out + NK * E_;
  u16* v1out = qout  + (size_t)B_ * E_;
  u16* Wt    = v1out + (size_t)B_ * E_;        // 4 * 1024*1024 bf16

  dim3 g0(16, 16, 4);
  wconv_kernel<<<g0, 256, 0, stream>>>(Wq, Wk, Wv1, Wv2, Wt);

  dim3 g1(8, 788);
  proj_kernel<<<g1, 256, 0, stream>>>(query, key, value1, value2,
      bq, gqw, gqb, bk, gkw, gkb, bv1, gv1w, gv1b, bv2, gv2w, gv2b,
      Wt, qout, kout, v1out, v2out);

  dim3 g2(H_, B_);
  attn_kernel<<<g2, 256, 0, stream>>>(qout, kout, v1out, v2out, mask,
      Wb, bb, Ws, bs, Wc, bc, (float*)d_out);
}

// Round 6
// 829.787 us; speedup vs baseline: 1.2503x; 1.2503x over previous
//
#include <hip/hip_runtime.h>

typedef unsigned short u16;
typedef unsigned int u32;
typedef __attribute__((ext_vector_type(8))) short short8;
typedef __attribute__((ext_vector_type(4))) float floatx4;

#define E_ 1024
#define B_ 256
#define M_ 196
#define H_ 8
#define DH_ 128
#define MID_ 64

__device__ __forceinline__ u16 f2bf(float f){
  union { float f; u32 u; } v; v.f = f;
  return (u16)((v.u + (((v.u >> 16) & 1u) + 0x7fffu)) >> 16);
}
__device__ __forceinline__ float bf2f(u16 h){
  union { u32 u; float f; } v; v.u = ((u32)h) << 16;
  return v.f;
}
// pack two floats to bf16x2
__device__ __forceinline__ u32 pack_bf2(float a, float b){
  u32 ua = __float_as_uint(a) + 0x8000u;
  u32 ub = __float_as_uint(b) + 0x8000u;
  return __builtin_amdgcn_perm(ub, ua, 0x07060302);
}
// async global->LDS, 16B per lane; LDS dest = base + lane*16 (wave-uniform base)
__device__ __forceinline__ void gl_lds16(const void* g, void* l){
  __builtin_amdgcn_global_load_lds(
      (const __attribute__((address_space(1))) u32*)g,
      (__attribute__((address_space(3))) u32*)l, 16, 0, 0);
}

// ---------------------------------------------------------------------------
// Kernel 0: convert+transpose the 4 projection weight matrices to bf16 [col][k].
// ---------------------------------------------------------------------------
__global__ __launch_bounds__(256) void wconv_kernel(
    const float* __restrict__ Wq, const float* __restrict__ Wk,
    const float* __restrict__ Wv1, const float* __restrict__ Wv2,
    u16* __restrict__ Wt)
{
  __shared__ u16 tile[64][72];
  const float* W = (blockIdx.z == 0) ? Wq : (blockIdx.z == 1) ? Wk
                 : (blockIdx.z == 2) ? Wv1 : Wv2;
  u16* out = Wt + (size_t)blockIdx.z * (E_ * E_);
  int k0 = blockIdx.x * 64, c0 = blockIdx.y * 64;
  int tx = threadIdx.x & 63, ty = threadIdx.x >> 6;
  #pragma unroll
  for (int i = 0; i < 16; i++){
    int k = ty * 16 + i;
    tile[k][tx] = f2bf(W[(size_t)(k0 + k) * E_ + c0 + tx]);
  }
  __syncthreads();
  #pragma unroll
  for (int i = 0; i < 16; i++){
    int c = ty * 16 + i;
    out[(size_t)(c0 + c) * E_ + k0 + tx] = tile[tx][c];
  }
}

// ---------------------------------------------------------------------------
// Kernel 1: fused GEMM + bias + celu + group-norm.
// 128x128 tile, BK=32, DOUBLE-BUFFERED LDS with ONE barrier per K-step:
//   barrier -> issue stage(kt+1) into buf^1 -> compute(kt) from buf.
// Stage latency (gl_lds B + reg-prefetch A) hides under a full compute phase
// instead of draining immediately (the round-3 stall).
// XCD-chunked block swizzle: bid&7 selects the XCD (consecutive hw ids
// round-robin XCDs); each XCD gets a contiguous run of row-tiles with all 8
// col-tiles, so the fp32 A slab is fetched ~once per XCD (L2-resident).
// Swizzles (BK=32, 64B row stride): slot = chunk ^ ((row>>1)&3); read
// slot = qd ^ ((lr>>1)&3). Verified: A-read, B-read, A-write all spread
// 8 lanes over 8 bank-quads (2-way over 16 = free). B staged via gl_lds
// with pre-swizzled global source chunk (l&3)^((l>>3)&3).
// ---------------------------------------------------------------------------
__global__ __launch_bounds__(256, 3) void proj_kernel(
    const float* __restrict__ query, const float* __restrict__ key,
    const float* __restrict__ value1, const float* __restrict__ value2,
    const float* __restrict__ bq, const float* __restrict__ gqw, const float* __restrict__ gqb,
    const float* __restrict__ bk, const float* __restrict__ gkw, const float* __restrict__ gkb,
    const float* __restrict__ bv1, const float* __restrict__ gv1w, const float* __restrict__ gv1b,
    const float* __restrict__ bv2, const float* __restrict__ gv2w, const float* __restrict__ gv2b,
    const u16* __restrict__ Wt,
    u16* __restrict__ qout, u16* __restrict__ kout,
    u16* __restrict__ v1out, u16* __restrict__ v2out)
{
  __shared__ u16 a_lds[2][128 * 32];  // 2 x 8 KB, row stride 64B, XOR-swizzled
  __shared__ u16 b_lds[2][128 * 32];  // 2 x 8 KB, col stride 64B, XOR-swizzled
  __shared__ float ps[128][2][2];     // per-row {s,s2} partials per ch-half

  const int tid = threadIdx.x;
  const int w = tid >> 6, lane = tid & 63, qd = lane >> 4, lr = lane & 15;
  const int rh = w >> 1, ch = w & 1;

  // XCD-chunked bijective swizzle (6304 = 8 * 788 blocks)
  const int bid = blockIdx.x;
  const int wgl = (bid & 7) * 788 + (bid >> 3);
  const int mtb = wgl >> 3;             // row-tile 0..787
  const int col0 = (wgl & 7) * 128;     // col-tile 0..7

  const float* X; const float *bias, *gw, *gb; u16* out; int row0, matsel;
  if (mtb < 392)      { X = key;    bias = bk;  gw = gkw;  gb = gkb;  out = kout;  row0 = mtb * 128;         matsel = 1; }
  else if (mtb < 784) { X = value2; bias = bv2; gw = gv2w; gb = gv2b; out = v2out; row0 = (mtb - 392) * 128; matsel = 3; }
  else if (mtb < 786) { X = query;  bias = bq;  gw = gqw;  gb = gqb;  out = qout;  row0 = (mtb - 784) * 128; matsel = 0; }
  else                { X = value1; bias = bv1; gw = gv1w; gb = gv1b; out = v1out; row0 = (mtb - 786) * 128; matsel = 2; }

  // A staging: thread t -> row t>>1, 16-float half t&1 of the BK=32 slab.
  const int ar = tid >> 1, ah = tid & 1;
  const int asw = (ar >> 1) & 3;
  const float* aSrc = X + (size_t)(row0 + ar) * E_ + ah * 16;
  // B staging: wave w covers cols [w*32,+32) in 2 gl_lds calls of 16 cols;
  // lane l -> col +(l>>2), pre-swizzled global chunk (l&3)^((l>>3)&3).
  const u16* bSrc = Wt + (size_t)matsel * (E_ * E_)
                  + (size_t)(col0 + w * 32 + (lane >> 2)) * E_
                  + ((lane & 3) ^ ((lane >> 3) & 3)) * 8;
  const int rsl = (qd ^ ((lr >> 1) & 3)) * 8;   // read slot (u16 offset)

  floatx4 acc[4][4];
  #pragma unroll
  for (int i = 0; i < 4; i++)
    #pragma unroll
    for (int j = 0; j < 4; j++){
      floatx4 z = {0.f, 0.f, 0.f, 0.f};
      acc[i][j] = z;
    }

  float4 aR[4];
  // kt=0 A data
  aR[0] = *(const float4*)(aSrc);
  aR[1] = *(const float4*)(aSrc + 4);
  aR[2] = *(const float4*)(aSrc + 8);
  aR[3] = *(const float4*)(aSrc + 12);
  // stage kt=0 -> buf0
  gl_lds16(bSrc,           &b_lds[0][(w * 32     ) * 32]);
  gl_lds16(bSrc + 16 * E_, &b_lds[0][(w * 32 + 16) * 32]);
  {
    union { u32 u[4]; int4 v; } p0, p1;
    p0.u[0] = pack_bf2(aR[0].x, aR[0].y);
    p0.u[1] = pack_bf2(aR[0].z, aR[0].w);
    p0.u[2] = pack_bf2(aR[1].x, aR[1].y);
    p0.u[3] = pack_bf2(aR[1].z, aR[1].w);
    p1.u[0] = pack_bf2(aR[2].x, aR[2].y);
    p1.u[1] = pack_bf2(aR[2].z, aR[2].w);
    p1.u[2] = pack_bf2(aR[3].x, aR[3].y);
    p1.u[3] = pack_bf2(aR[3].z, aR[3].w);
    *(int4*)&a_lds[0][ar * 32 + (((ah * 2)     ^ asw)) * 8] = p0.v;
    *(int4*)&a_lds[0][ar * 32 + (((ah * 2 + 1) ^ asw)) * 8] = p1.v;
  }
  // prefetch kt=1 A data
  aR[0] = *(const float4*)(aSrc + 32);
  aR[1] = *(const float4*)(aSrc + 36);
  aR[2] = *(const float4*)(aSrc + 40);
  aR[3] = *(const float4*)(aSrc + 44);

#define PROJ_STEP(KT, CUR, NXT)                                               \
  {                                                                           \
    __syncthreads();   /* drains stage(KT) issued last iter (had a full   */  \
                       /* compute phase to land); fences reads of buf NXT */  \
    if ((KT) < 31){                                                           \
      const int kn = ((KT) + 1) * 32;                                         \
      gl_lds16(bSrc + kn,           &b_lds[NXT][(w * 32     ) * 32]);         \
      gl_lds16(bSrc + kn + 16 * E_, &b_lds[NXT][(w * 32 + 16) * 32]);         \
      union { u32 u[4]; int4 v; } p0, p1;                                     \
      p0.u[0] = pack_bf2(aR[0].x, aR[0].y);                                   \
      p0.u[1] = pack_bf2(aR[0].z, aR[0].w);                                   \
      p0.u[2] = pack_bf2(aR[1].x, aR[1].y);                                   \
      p0.u[3] = pack_bf2(aR[1].z, aR[1].w);                                   \
      p1.u[0] = pack_bf2(aR[2].x, aR[2].y);                                   \
      p1.u[1] = pack_bf2(aR[2].z, aR[2].w);                                   \
      p1.u[2] = pack_bf2(aR[3].x, aR[3].y);                                   \
      p1.u[3] = pack_bf2(aR[3].z, aR[3].w);                                   \
      *(int4*)&a_lds[NXT][ar * 32 + (((ah * 2)     ^ asw)) * 8] = p0.v;       \
      *(int4*)&a_lds[NXT][ar * 32 + (((ah * 2 + 1) ^ asw)) * 8] = p1.v;       \
      if ((KT) < 30){                                                         \
        const int kp = ((KT) + 2) * 32;                                       \
        aR[0] = *(const float4*)(aSrc + kp);                                  \
        aR[1] = *(const float4*)(aSrc + kp + 4);                              \
        aR[2] = *(const float4*)(aSrc + kp + 8);                              \
        aR[3] = *(const float4*)(aSrc + kp + 12);                             \
      }                                                                       \
    }                                                                         \
    short8 bfr0 = *(const short8*)&b_lds[CUR][(ch * 64      + lr) * 32 + rsl];\
    short8 bfr1 = *(const short8*)&b_lds[CUR][(ch * 64 + 16 + lr) * 32 + rsl];\
    short8 bfr2 = *(const short8*)&b_lds[CUR][(ch * 64 + 32 + lr) * 32 + rsl];\
    short8 bfr3 = *(const short8*)&b_lds[CUR][(ch * 64 + 48 + lr) * 32 + rsl];\
    _Pragma("unroll")                                                         \
    for (int m2 = 0; m2 < 4; m2++){                                           \
      short8 afr = *(const short8*)&a_lds[CUR][(rh * 64 + m2 * 16 + lr) * 32 + rsl]; \
      acc[m2][0] = __builtin_amdgcn_mfma_f32_16x16x32_bf16(afr, bfr0, acc[m2][0], 0, 0, 0); \
      acc[m2][1] = __builtin_amdgcn_mfma_f32_16x16x32_bf16(afr, bfr1, acc[m2][1], 0, 0, 0); \
      acc[m2][2] = __builtin_amdgcn_mfma_f32_16x16x32_bf16(afr, bfr2, acc[m2][2], 0, 0, 0); \
      acc[m2][3] = __builtin_amdgcn_mfma_f32_16x16x32_bf16(afr, bfr3, acc[m2][3], 0, 0, 0); \
    }                                                                         \
  }

  for (int kt = 0; kt < 32; kt += 2){
    PROJ_STEP(kt,     0, 1)
    PROJ_STEP(kt + 1, 1, 0)
  }
#undef PROJ_STEP

  // Epilogue: bias + celu; per-row stats over the full 128-col group
  // (in-wave over this wave's 64 cols, then cross-ch combine in LDS).
  float biasv[4], gwv[4], gbv[4];
  #pragma unroll
  for (int nt = 0; nt < 4; nt++){
    int c = col0 + ch * 64 + nt * 16 + lr;
    biasv[nt] = bias[c]; gwv[nt] = gw[c]; gbv[nt] = gb[c];
  }
  #pragma unroll
  for (int m2 = 0; m2 < 4; m2++){
    #pragma unroll
    for (int r = 0; r < 4; r++){
      float s = 0.f, s2 = 0.f;
      #pragma unroll
      for (int nt = 0; nt < 4; nt++){
        float x = acc[m2][nt][r] + biasv[nt];
        x = (x > 0.f) ? x : 1.3f * expm1f(x * (1.0f / 1.3f));
        acc[m2][nt][r] = x;
        s += x; s2 += x * x;
      }
      #pragma unroll
      for (int off = 1; off < 16; off <<= 1){
        s  += __shfl_xor(s,  off, 64);
        s2 += __shfl_xor(s2, off, 64);
      }
      if (lr == 0){
        int row = rh * 64 + m2 * 16 + qd * 4 + r;
        ps[row][ch][0] = s; ps[row][ch][1] = s2;
      }
    }
  }
  __syncthreads();
  #pragma unroll
  for (int m2 = 0; m2 < 4; m2++){
    #pragma unroll
    for (int r = 0; r < 4; r++){
      int row = rh * 64 + m2 * 16 + qd * 4 + r;
      float s  = ps[row][0][0] + ps[row][1][0];
      float s2 = ps[row][0][1] + ps[row][1][1];
      float mean = s * 0.0078125f;
      float var  = s2 * 0.0078125f - mean * mean;
      float rstd = rsqrtf(var + 1e-5f);
      size_t base = (size_t)(row0 + row) * E_ + col0 + ch * 64;
      #pragma unroll
      for (int nt = 0; nt < 4; nt++)
        out[base + nt * 16 + lr] = f2bf((acc[m2][nt][r] - mean) * rstd * gwv[nt] + gbv[nt]);
    }
  }
}

// ---------------------------------------------------------------------------
// Kernel 2: per-(b,h) attention. (unchanged this round)
// ---------------------------------------------------------------------------
__global__ __launch_bounds__(256) void attn_kernel(
    const u16* __restrict__ qproj, const u16* __restrict__ kproj,
    const u16* __restrict__ v1proj, const u16* __restrict__ v2proj,
    const int* __restrict__ mask,
    const float* __restrict__ Wb, const float* __restrict__ bb,
    const float* __restrict__ Ws, const float* __restrict__ bs,
    const float* __restrict__ Wc, const float* __restrict__ bc,
    float* __restrict__ outp)
{
  __shared__ u16 wbt[64 * 136];      // B' = diag(q)*Wb, [n][k], stride 136
  __shared__ float qv[128];
  __shared__ float mrow[208];
  __shared__ float logitv[208];
  __shared__ float hsum_l[4][64];
  __shared__ float wexpv[208];
  __shared__ float poolv[64];
  __shared__ float v2acc[4][128];
  __shared__ float red[8];

  const int tid = threadIdx.x;
  const int w = tid >> 6, lane = tid & 63, qd = lane >> 4, lr = lane & 15;
  const int b = blockIdx.y, h = blockIdx.x;

  const u16* kbase  = kproj  + (size_t)b * M_ * E_ + h * DH_;
  const u16* v2base = v2proj + (size_t)b * M_ * E_ + h * DH_;

  if (tid < 128) qv[tid] = bf2f(qproj[(size_t)b * E_ + h * DH_ + tid]);
  if (tid < 208) mrow[tid] = (tid < M_) ? (float)mask[b * M_ + tid] : 0.f;
  __syncthreads();

  {
    int n = tid & 63, kb = (tid >> 6) * 32;
    #pragma unroll
    for (int kk = 0; kk < 32; kk++)
      wbt[n * 136 + kb + kk] = f2bf(qv[kb + kk] * Wb[(kb + kk) * MID_ + n]);
  }
  __syncthreads();

  float wsv[4], bbv[4];
  #pragma unroll
  for (int nt = 0; nt < 4; nt++){ wsv[nt] = Ws[nt * 16 + lr]; bbv[nt] = bb[nt * 16 + lr]; }
  const float bsv = bs[0];
  float hs[4] = {0, 0, 0, 0};

  for (int mt = w; mt < 13; mt += 4){
    int mrow_g = mt * 16 + lr;
    int mcl = (mrow_g < M_) ? mrow_g : (M_ - 1);   // clamp padded rows
    const u16* arow = kbase + (size_t)mcl * E_;
    floatx4 hacc[4];
    #pragma unroll
    for (int nt = 0; nt < 4; nt++){ floatx4 z = {0.f, 0.f, 0.f, 0.f}; hacc[nt] = z; }
    #pragma unroll
    for (int kc = 0; kc < 4; kc++){
      short8 afr = *(const short8*)(arow + kc * 32 + qd * 8);
      #pragma unroll
      for (int nt = 0; nt < 4; nt++){
        short8 bfr = *(const short8*)&wbt[(nt * 16 + lr) * 136 + kc * 32 + qd * 8];
        hacc[nt] = __builtin_amdgcn_mfma_f32_16x16x32_bf16(afr, bfr, hacc[nt], 0, 0, 0);
      }
    }
    float lp[4] = {0, 0, 0, 0};
    #pragma unroll
    for (int nt = 0; nt < 4; nt++){
      #pragma unroll
      for (int r = 0; r < 4; r++){
        float hv = hacc[nt][r] + bbv[nt];
        hv = fmaxf(hv, 0.f);
        lp[r] += hv * wsv[nt];
        hs[nt] += mrow[mt * 16 + qd * 4 + r] * hv;
      }
    }
    #pragma unroll
    for (int r = 0; r < 4; r++){
      float a = lp[r];
      #pragma unroll
      for (int off = 1; off < 16; off <<= 1) a += __shfl_xor(a, off, 64);
      if (lr == 0) logitv[mt * 16 + qd * 4 + r] = a + bsv;
    }
  }
  #pragma unroll
  for (int nt = 0; nt < 4; nt++){
    hs[nt] += __shfl_xor(hs[nt], 16, 64);
    hs[nt] += __shfl_xor(hs[nt], 32, 64);
  }
  if (lane < 16){
    #pragma unroll
    for (int nt = 0; nt < 4; nt++) hsum_l[w][nt * 16 + lane] = hs[nt];
  }
  __syncthreads();

  if (w == 0){
    float s = 0.f;
    for (int m = lane; m < M_; m += 64) s += mrow[m];
    #pragma unroll
    for (int off = 1; off < 64; off <<= 1) s += __shfl_xor(s, off, 64);
    if (lane == 0) red[0] = s;
  } else if (w == 1){
    float mx = -1e30f;
    for (int m = lane; m < M_; m += 64) if (mrow[m] > 0.5f) mx = fmaxf(mx, logitv[m]);
    #pragma unroll
    for (int off = 1; off < 64; off <<= 1) mx = fmaxf(mx, __shfl_xor(mx, off, 64));
    if (lane == 0) red[1] = mx;
  } else if (w == 2){
    poolv[lane & 63] = hsum_l[0][lane & 63] + hsum_l[1][lane & 63]
                     + hsum_l[2][lane & 63] + hsum_l[3][lane & 63];
  }
  __syncthreads();
  const float cnt = red[0], mx = red[1];
  if (tid < 208)
    wexpv[tid] = (tid < M_ && mrow[tid] > 0.5f) ? expf(logitv[tid] - mx) : 0.f;
  __syncthreads();
  if (w == 0){
    float s = 0.f;
    for (int m = lane; m < M_; m += 64) s += wexpv[m];
    #pragma unroll
    for (int off = 1; off < 64; off <<= 1) s += __shfl_xor(s, off, 64);
    if (lane == 0) red[2] = s;
  } else if (w == 1){
    poolv[lane & 63] = poolv[lane & 63] / cnt;
  }
  __syncthreads();
  const float S = red[2];

  // v2 pooling: per iteration a wave covers rows {it*16 + w*4 + qd}, 16B/lane.
  {
    float ac[8] = {0, 0, 0, 0, 0, 0, 0, 0};
    #pragma unroll
    for (int it = 0; it < 13; it++){
      int m = it * 16 + w * 4 + qd;
      if (m < M_){
        float we = wexpv[m];
        uint4 u = *(const uint4*)(v2base + (size_t)m * E_ + lr * 8);
        ac[0] += we * bf2f((u16)(u.x & 0xffff));
        ac[1] += we * bf2f((u16)(u.x >> 16));
        ac[2] += we * bf2f((u16)(u.y & 0xffff));
        ac[3] += we * bf2f((u16)(u.y >> 16));
        ac[4] += we * bf2f((u16)(u.z & 0xffff));
        ac[5] += we * bf2f((u16)(u.z >> 16));
        ac[6] += we * bf2f((u16)(u.w & 0xffff));
        ac[7] += we * bf2f((u16)(u.w >> 16));
      }
    }
    #pragma unroll
    for (int j = 0; j < 8; j++){
      ac[j] += __shfl_xor(ac[j], 16, 64);
      ac[j] += __shfl_xor(ac[j], 32, 64);
    }
    if (qd == 0){
      #pragma unroll
      for (int j = 0; j < 8; j++) v2acc[w][lr * 8 + j] = ac[j];
    }
  }
  __syncthreads();

  if (tid < 128){
    float a = 0.f;
    #pragma unroll 8
    for (int j = 0; j < 64; j++) a += poolv[j] * Wc[j * DH_ + tid];
    float acv = 1.f / (1.f + expf(-(a + bc[tid])));
    float vp = (v2acc[0][tid] + v2acc[1][tid] + v2acc[2][tid] + v2acc[3][tid]) / S;
    float o = bf2f(v1proj[(size_t)b * E_ + h * DH_ + tid]) * vp * acv;
    outp[(size_t)b * E_ + h * DH_ + tid] = o;
  }
}

// ---------------------------------------------------------------------------
extern "C" void kernel_launch(void* const* d_in, const int* in_sizes, int n_in,
                              void* d_out, int out_size, void* d_ws, size_t ws_size,
                              hipStream_t stream)
{
  const float* query  = (const float*)d_in[0];
  const float* key    = (const float*)d_in[1];
  const int*   mask   = (const int*)d_in[2];
  const float* value1 = (const float*)d_in[3];
  const float* value2 = (const float*)d_in[4];
  const float* Wq  = (const float*)d_in[5];
  const float* bq  = (const float*)d_in[6];
  const float* gqw = (const float*)d_in[7];
  const float* gqb = (const float*)d_in[8];
  const float* Wk  = (const float*)d_in[9];
  const float* bk  = (const float*)d_in[10];
  const float* gkw = (const float*)d_in[11];
  const float* gkb = (const float*)d_in[12];
  const float* Wv1 = (const float*)d_in[13];
  const float* bv1 = (const float*)d_in[14];
  const float* gv1w= (const float*)d_in[15];
  const float* gv1b= (const float*)d_in[16];
  const float* Wv2 = (const float*)d_in[17];
  const float* bv2 = (const float*)d_in[18];
  const float* gv2w= (const float*)d_in[19];
  const float* gv2b= (const float*)d_in[20];
  const float* Wb  = (const float*)d_in[21];
  const float* bb  = (const float*)d_in[22];
  const float* Ws  = (const float*)d_in[23];
  const float* bs  = (const float*)d_in[24];
  const float* Wc  = (const float*)d_in[25];
  const float* bc  = (const float*)d_in[26];

  const size_t NK = (size_t)B_ * M_;           // 50176 rows
  u16* kout  = (u16*)d_ws;
  u16* v2out = kout  + NK * E_;
  u16* qout  = v2out + NK * E_;
  u16* v1out = qout  + (size_t)B_ * E_;
  u16* Wt    = v1out + (size_t)B_ * E_;        // 4 * 1024*1024 bf16

  dim3 g0(16, 16, 4);
  wconv_kernel<<<g0, 256, 0, stream>>>(Wq, Wk, Wv1, Wv2, Wt);

  dim3 g1(6304);
  proj_kernel<<<g1, 256, 0, stream>>>(query, key, value1, value2,
      bq, gqw, gqb, bk, gkw, gkb, bv1, gv1w, gv1b, bv2, gv2w, gv2b,
      Wt, qout, kout, v1out, v2out);

  dim3 g2(H_, B_);
  attn_kernel<<<g2, 256, 0, stream>>>(qout, kout, v1out, v2out, mask,
      Wb, bb, Ws, bs, Wc, bc, (float*)d_out);
}